// Round 10
// baseline (374.709 us; speedup 1.0000x reference)
//
#include <hip/hip_runtime.h>
#include <hip/hip_fp16.h>
#include <cmath>

#define NLEV 16
#define HASH_START 12               // levels >= 12 use spatial hash ((r+1)^2 > 2^19)
#define HMASK ((1u << 19) - 1u)     // hash level size is exactly 2^19
#define HASH_PRIME 2654435761u
#define LDSA_WORDS 7432             // offset[5]: entries of levels 0-4 (host-guarded)
#define LDS5_WORDS 6728             // size of level 5 (host-guarded)

typedef float    f4 __attribute__((ext_vector_type(4)));
typedef unsigned u4 __attribute__((ext_vector_type(4)));

struct LvlC {
  float scale[NLEV];
  unsigned stride[NLEV];   // res + 1
  unsigned offset[NLEV];   // cumulative param offset (multiple of 8)
};

__device__ __forceinline__ float2 h2f(unsigned u) {
  return __half22float2(__builtin_bit_cast(__half2, u));
}
__device__ __forceinline__ void nt_store4(float* p, float a, float b, float c, float d) {
  f4 v = {a, b, c, d};
  __builtin_nontemporal_store(v, reinterpret_cast<f4*>(p));
}

// ---- pass 0: fp32 tables -> fp16 copies in ws ----
__global__ __launch_bounds__(256) void k_convert(
    const float2* __restrict__ t0, const float2* __restrict__ t1,
    const float2* __restrict__ t2, unsigned* __restrict__ dst, unsigned total)
{
  unsigned g = blockIdx.x * 256 + threadIdx.x;
  unsigned stp = gridDim.x * 256;
  unsigned tot3 = 3u * total;
  for (unsigned e = g; e < tot3; e += stp) {
    const float2* src; unsigned i = e;
    if (i < total)            { src = t0; }
    else if (i < 2u * total)  { src = t1; i -= total; }
    else                      { src = t2; i -= 2u * total; }
    float2 v = src[i];
    __half2 h = __floats2half2_rn(v.x, v.y);
    __builtin_nontemporal_store(__builtin_bit_cast(unsigned, h), dst + e);
  }
}

// ---- dense levels 10,11: 2 pts/thread -> 2 slices ----
__global__ __launch_bounds__(256) void k_dense1011(
    const float* __restrict__ pts, const unsigned* __restrict__ tab,
    unsigned* __restrict__ s10, unsigned* __restrict__ s11,
    LvlC lc, unsigned total, int half)
{
  int t = blockIdx.x * 256 + threadIdx.x;
  if (t >= half) return;
  const int idx[2] = {t, t + half};

  float ua[2][3], ub[2][3];
#pragma unroll
  for (int k = 0; k < 2; ++k) {
    float u0 = (pts[3 * idx[k] + 0] + 1.f) * .5f;
    float u1 = (pts[3 * idx[k] + 1] + 1.f) * .5f;
    float u2 = (pts[3 * idx[k] + 2] + 1.f) * .5f;
    ua[k][0] = u0; ub[k][0] = u1;
    ua[k][1] = u0; ub[k][1] = u2;
    ua[k][2] = u1; ub[k][2] = u2;
  }

  uint2 g[2][2][3][2];
  float rx[2][2][3], ry[2][2][3];
#pragma unroll
  for (int k = 0; k < 2; ++k)
#pragma unroll
    for (int l = 0; l < 2; ++l) {
      const float sc = lc.scale[10 + l];
      const unsigned st = lc.stride[10 + l], o = lc.offset[10 + l];
#pragma unroll
      for (int p = 0; p < 3; ++p) {
        float px = ua[k][p] * sc + .5f, py = ub[k][p] * sc + .5f;
        float fx = floorf(px), fy = floorf(py);
        rx[k][l][p] = px - fx; ry[k][l][p] = py - fy;
        unsigned i00 = (unsigned)fx + (unsigned)fy * st + o;
        const unsigned* tp = tab + (size_t)p * total;
        g[k][l][p][0] = *reinterpret_cast<const uint2*>(tp + i00);
        g[k][l][p][1] = *reinterpret_cast<const uint2*>(tp + i00 + st);
      }
    }

#pragma unroll
  for (int k = 0; k < 2; ++k)
#pragma unroll
    for (int l = 0; l < 2; ++l) {
      float s0 = 0.f, s1 = 0.f;
#pragma unroll
      for (int p = 0; p < 3; ++p) {
        float x = rx[k][l][p], y = ry[k][l][p];
        float w00 = (1.f - x) * (1.f - y), w10 = x * (1.f - y);
        float w01 = (1.f - x) * y,          w11 = x * y;
        float2 f00 = h2f(g[k][l][p][0].x), f10 = h2f(g[k][l][p][0].y);
        float2 f01 = h2f(g[k][l][p][1].x), f11 = h2f(g[k][l][p][1].y);
        s0 += w00 * f00.x + w10 * f10.x + w01 * f01.x + w11 * f11.x;
        s1 += w00 * f00.y + w10 * f10.y + w01 * f01.y + w11 * f11.y;
      }
      unsigned hv = __builtin_bit_cast(unsigned, __floats2half2_rn(s0, s1));
      unsigned* sl = l ? s11 : s10;
      __builtin_nontemporal_store(hv, sl + idx[k]);
    }
}

// even-x0 trick: (x0+1)^hy == (x0^hy)^1 when x0 even -> aligned uint2 pair
__device__ __forceinline__ void hash_row(
    const unsigned* __restrict__ tp, unsigned x0, unsigned hy,
    unsigned& g0, unsigned& g1)
{
  unsigned a0 = (x0 ^ hy) & HMASK;
  if ((x0 & 1u) == 0u) {
    uint2 v = *reinterpret_cast<const uint2*>(tp + (a0 & ~1u));
    bool hi = (a0 & 1u) != 0u;
    g0 = hi ? v.y : v.x;
    g1 = hi ? v.x : v.y;
  } else {
    g0 = tp[a0];
    g1 = tp[((x0 + 1u) ^ hy) & HMASK];
  }
}

// ---- one hash level, all 3 planes, 2 pts/thread ----
__global__ __launch_bounds__(256) void k_hash_lvl(
    const float* __restrict__ pts, const unsigned* __restrict__ tab,
    unsigned* __restrict__ slice, float sc, unsigned o, unsigned total, int half)
{
  int t = blockIdx.x * 256 + threadIdx.x;
  if (t >= half) return;
  const int idx[2] = {t, t + half};

  float ua[2][3], ub[2][3];
#pragma unroll
  for (int k = 0; k < 2; ++k) {
    float u0 = (pts[3 * idx[k] + 0] + 1.f) * .5f;
    float u1 = (pts[3 * idx[k] + 1] + 1.f) * .5f;
    float u2 = (pts[3 * idx[k] + 2] + 1.f) * .5f;
    ua[k][0] = u0; ub[k][0] = u1;
    ua[k][1] = u0; ub[k][1] = u2;
    ua[k][2] = u1; ub[k][2] = u2;
  }

  unsigned g[2][3][4];
  float rx[2][3], ry[2][3];
#pragma unroll
  for (int k = 0; k < 2; ++k)
#pragma unroll
    for (int p = 0; p < 3; ++p) {
      float px = ua[k][p] * sc + .5f, py = ub[k][p] * sc + .5f;
      float fx = floorf(px), fy = floorf(py);
      rx[k][p] = px - fx; ry[k][p] = py - fy;
      unsigned x0 = (unsigned)fx, y0 = (unsigned)fy;
      unsigned hy0 = y0 * HASH_PRIME, hy1 = hy0 + HASH_PRIME;
      const unsigned* tp = tab + (size_t)p * total + o;
      hash_row(tp, x0, hy0, g[k][p][0], g[k][p][1]);
      hash_row(tp, x0, hy1, g[k][p][2], g[k][p][3]);
    }

#pragma unroll
  for (int k = 0; k < 2; ++k) {
    float s0 = 0.f, s1 = 0.f;
#pragma unroll
    for (int p = 0; p < 3; ++p) {
      float x = rx[k][p], y = ry[k][p];
      float w00 = (1.f - x) * (1.f - y), w10 = x * (1.f - y);
      float w01 = (1.f - x) * y,          w11 = x * y;
      float2 f00 = h2f(g[k][p][0]), f10 = h2f(g[k][p][1]);
      float2 f01 = h2f(g[k][p][2]), f11 = h2f(g[k][p][3]);
      s0 += w00 * f00.x + w10 * f10.x + w01 * f01.x + w11 * f11.x;
      s1 += w00 * f00.y + w10 * f10.y + w01 * f01.y + w11 * f11.y;
    }
    __builtin_nontemporal_store(
        __builtin_bit_cast(unsigned, __floats2half2_rn(s0, s1)), slice + idx[k]);
  }
}

// ---- final: LDS levels 0-5 in SIX small phases (29.7KB buffer -> 4 blk/CU)
//      + levels 6-9 global + slice merge; PLAIN row stores (L2 write-merge) ----
__global__ __launch_bounds__(512) void k_final(
    const float* __restrict__ pts, const unsigned* __restrict__ tab,
    const unsigned* __restrict__ slices,   // 6 x n, levels 10..15
    float* __restrict__ out, LvlC lc, unsigned total, int n)
{
  __shared__ unsigned lds[LDSA_WORDS];     // reused for level-5 phase (6728 < 7432)
  int i = blockIdx.x * 512 + threadIdx.x;  // n % 512 == 0 (host-guarded)

  // slice reads issued early (coalesced; overlap with LDS phases)
  unsigned sl[6];
#pragma unroll
  for (int j = 0; j < 6; ++j) sl[j] = slices[(size_t)j * n + i];

  float u0 = (pts[3 * i + 0] + 1.f) * .5f;
  float u1 = (pts[3 * i + 1] + 1.f) * .5f;
  float u2 = (pts[3 * i + 2] + 1.f) * .5f;
  const float ua[3] = {u0, u0, u1}, ub[3] = {u1, u2, u2};

  float res[12];
#pragma unroll
  for (int j = 0; j < 12; ++j) res[j] = 0.f;

  // --- levels 0-5, per plane: {stage 0-4, compute 0-4, stage 5, compute 5} ---
  for (int p = 0; p < 3; ++p) {
    const unsigned* tp = tab + (size_t)p * total;
    if (p) __syncthreads();
    for (unsigned e = threadIdx.x; e < LDSA_WORDS / 4; e += 512)
      reinterpret_cast<u4*>(lds)[e] = reinterpret_cast<const u4*>(tp)[e];
    __syncthreads();
#pragma unroll
    for (int l = 0; l < 5; ++l) {
      float px = ua[p] * lc.scale[l] + .5f, py = ub[p] * lc.scale[l] + .5f;
      float fx = floorf(px), fy = floorf(py);
      float x = px - fx, y = py - fy;
      unsigned st = lc.stride[l];
      unsigned i00 = (unsigned)fx + (unsigned)fy * st + lc.offset[l];
      float2 f00 = h2f(lds[i00]),      f10 = h2f(lds[i00 + 1]);
      float2 f01 = h2f(lds[i00 + st]), f11 = h2f(lds[i00 + st + 1]);
      float w00 = (1.f - x) * (1.f - y), w10 = x * (1.f - y);
      float w01 = (1.f - x) * y,          w11 = x * y;
      res[2 * l + 0] += w00 * f00.x + w10 * f10.x + w01 * f01.x + w11 * f11.x;
      res[2 * l + 1] += w00 * f00.y + w10 * f10.y + w01 * f01.y + w11 * f11.y;
    }
    __syncthreads();
    {
      const u4* src5 = reinterpret_cast<const u4*>(tp + lc.offset[5]);
      for (unsigned e = threadIdx.x; e < LDS5_WORDS / 4; e += 512)
        reinterpret_cast<u4*>(lds)[e] = src5[e];
      __syncthreads();
      float px = ua[p] * lc.scale[5] + .5f, py = ub[p] * lc.scale[5] + .5f;
      float fx = floorf(px), fy = floorf(py);
      float x = px - fx, y = py - fy;
      unsigned st = lc.stride[5];
      unsigned i00 = (unsigned)fx + (unsigned)fy * st;   // level-5-local
      float2 f00 = h2f(lds[i00]),      f10 = h2f(lds[i00 + 1]);
      float2 f01 = h2f(lds[i00 + st]), f11 = h2f(lds[i00 + st + 1]);
      float w00 = (1.f - x) * (1.f - y), w10 = x * (1.f - y);
      float w01 = (1.f - x) * y,          w11 = x * y;
      res[10] += w00 * f00.x + w10 * f10.x + w01 * f01.x + w11 * f11.x;
      res[11] += w00 * f00.y + w10 * f10.y + w01 * f01.y + w11 * f11.y;
    }
  }

  // --- levels 6-9: two sequential pair-groups ---
  float res69[8];
#pragma unroll
  for (int grp = 0; grp < 2; ++grp) {
    uint2 g[2][3][2];
    float gx[2][3], gy[2][3];
#pragma unroll
    for (int h = 0; h < 2; ++h) {
      const int l = 6 + 2 * grp + h;
      const float sc = lc.scale[l];
      const unsigned st = lc.stride[l], o = lc.offset[l];
#pragma unroll
      for (int p = 0; p < 3; ++p) {
        float px = ua[p] * sc + .5f, py = ub[p] * sc + .5f;
        float fx = floorf(px), fy = floorf(py);
        gx[h][p] = px - fx; gy[h][p] = py - fy;
        unsigned i00 = (unsigned)fx + (unsigned)fy * st + o;
        const unsigned* tp = tab + (size_t)p * total;
        g[h][p][0] = *reinterpret_cast<const uint2*>(tp + i00);
        g[h][p][1] = *reinterpret_cast<const uint2*>(tp + i00 + st);
      }
    }
#pragma unroll
    for (int h = 0; h < 2; ++h) {
      float s0 = 0.f, s1 = 0.f;
#pragma unroll
      for (int p = 0; p < 3; ++p) {
        float x = gx[h][p], y = gy[h][p];
        float w00 = (1.f - x) * (1.f - y), w10 = x * (1.f - y);
        float w01 = (1.f - x) * y,          w11 = x * y;
        float2 f00 = h2f(g[h][p][0].x), f10 = h2f(g[h][p][0].y);
        float2 f01 = h2f(g[h][p][1].x), f11 = h2f(g[h][p][1].y);
        s0 += w00 * f00.x + w10 * f10.x + w01 * f01.x + w11 * f11.x;
        s1 += w00 * f00.y + w10 * f10.y + w01 * f01.y + w11 * f11.y;
      }
      res69[4 * grp + 2 * h + 0] = s0;
      res69[4 * grp + 2 * h + 1] = s1;
    }
  }

  float v[32];
#pragma unroll
  for (int j = 0; j < 12; ++j) v[j] = res[j];
#pragma unroll
  for (int j = 0; j < 8; ++j) v[12 + j] = res69[j];
#pragma unroll
  for (int j = 0; j < 6; ++j) {
    float2 f = h2f(sl[j]);
    v[20 + 2 * j] = f.x; v[20 + 2 * j + 1] = f.y;
  }
  // PLAIN stores: L2 allocates and merges the 8x16B into full 128B lines (R1: 131MB)
  float4* o4 = (float4*)(out + (size_t)i * 32);
#pragma unroll
  for (int j = 0; j < 8; ++j)
    o4[j] = make_float4(v[4 * j], v[4 * j + 1], v[4 * j + 2], v[4 * j + 3]);
}

// ---- fallback: monolithic fp32 (guards failed) ----
__global__ __launch_bounds__(256) void k_fallback(
    const float* __restrict__ pts, const float2* __restrict__ txy,
    const float2* __restrict__ txz, const float2* __restrict__ tyz,
    float* __restrict__ out, LvlC lc, int n)
{
  int i = blockIdx.x * 256 + threadIdx.x;
  if (i >= n) return;
  float u0 = (pts[3 * i + 0] + 1.f) * .5f;
  float u1 = (pts[3 * i + 1] + 1.f) * .5f;
  float u2 = (pts[3 * i + 2] + 1.f) * .5f;
  const float ua[3] = {u0, u0, u1}, ub[3] = {u1, u2, u2};
  const float2* tabs[3] = {txy, txz, tyz};
  float acc[32];
#pragma unroll
  for (int j = 0; j < 32; ++j) acc[j] = 0.f;
#pragma unroll
  for (int l = 0; l < NLEV; ++l) {
    const float sc = lc.scale[l];
    const unsigned o = lc.offset[l], s = lc.stride[l];
#pragma unroll
    for (int p = 0; p < 3; ++p) {
      const float2* t = tabs[p];
      float px = ua[p] * sc + .5f, py = ub[p] * sc + .5f;
      float fx = floorf(px), fy = floorf(py);
      float rx = px - fx, ry = py - fy;
      unsigned x0 = (unsigned)fx, y0 = (unsigned)fy;
      float w00 = (1.f - rx) * (1.f - ry), w10 = rx * (1.f - ry);
      float w01 = (1.f - rx) * ry,          w11 = rx * ry;
      float2 f00, f10, f01, f11;
      if (l >= HASH_START) {
        unsigned hy0 = y0 * HASH_PRIME, hy1 = hy0 + HASH_PRIME;
        f00 = t[o + ((x0 ^ hy0) & HMASK)];
        f10 = t[o + (((x0 + 1u) ^ hy0) & HMASK)];
        f01 = t[o + ((x0 ^ hy1) & HMASK)];
        f11 = t[o + (((x0 + 1u) ^ hy1) & HMASK)];
      } else {
        unsigned i00 = x0 + y0 * s;
        float4 r0 = *reinterpret_cast<const float4*>(t + o + i00);
        float4 r1 = *reinterpret_cast<const float4*>(t + o + i00 + s);
        f00 = make_float2(r0.x, r0.y); f10 = make_float2(r0.z, r0.w);
        f01 = make_float2(r1.x, r1.y); f11 = make_float2(r1.z, r1.w);
      }
      acc[2 * l + 0] += w00 * f00.x + w10 * f10.x + w01 * f01.x + w11 * f11.x;
      acc[2 * l + 1] += w00 * f00.y + w10 * f10.y + w01 * f01.y + w11 * f11.y;
    }
  }
  float4* o4 = (float4*)(out + (size_t)i * 32);
#pragma unroll
  for (int j = 0; j < 8; ++j)
    o4[j] = make_float4(acc[4 * j], acc[4 * j + 1], acc[4 * j + 2], acc[4 * j + 3]);
}

static unsigned compute_levels(LvlC* lc)
{
  // Mirrors Python _level_constants() with identical double-precision ops.
  const double pls = std::pow(2.0, std::log2(2048.0 / 16.0) / 15.0);
  unsigned long long off = 0;
  for (int l = 0; l < NLEV; ++l) {
    double s = 16.0 * std::pow(pls, (double)l) - 1.0;
    lc->scale[l] = (float)s;
    long long r = (long long)std::ceil(s) + 1;
    long long dense = (r + 1) * (r + 1);
    long long sz = dense < (1LL << 19) ? dense : (1LL << 19);
    sz = ((sz + 7) / 8) * 8;
    lc->stride[l] = (unsigned)(r + 1);
    lc->offset[l] = (unsigned)off;
    off += (unsigned long long)sz;
  }
  return (unsigned)off;
}

extern "C" void kernel_launch(void* const* d_in, const int* in_sizes, int n_in,
                              void* d_out, int out_size, void* d_ws, size_t ws_size,
                              hipStream_t stream) {
  const float*  pts = (const float*)d_in[0];
  const float2* txy = (const float2*)d_in[1];
  const float2* txz = (const float2*)d_in[2];
  const float2* tyz = (const float2*)d_in[3];
  float* out = (float*)d_out;
  int n = in_sizes[0] / 3;  // 1048576 points

  LvlC lc;
  unsigned total = compute_levels(&lc);

  size_t tab_bytes = (size_t)3 * total * 4;
  size_t tab_al = (tab_bytes + 255) & ~(size_t)255;
  size_t need = tab_al + (size_t)6 * n * 4;

  bool ok = (n % 512 == 0) && (lc.offset[5] == LDSA_WORDS) &&
            (lc.offset[6] - lc.offset[5] == LDS5_WORDS) && (ws_size >= need);
  for (int l = HASH_START; l < NLEV; ++l) {
    unsigned sz = ((l + 1 < NLEV) ? lc.offset[l + 1] : total) - lc.offset[l];
    ok = ok && (sz == (1u << 19));
  }

  int block = 256;
  int grid = (n + block - 1) / block;
  if (!ok) {
    k_fallback<<<grid, block, 0, stream>>>(pts, txy, txz, tyz, out, lc, n);
    return;
  }

  unsigned* tab16 = (unsigned*)d_ws;
  unsigned* slices = (unsigned*)((char*)d_ws + tab_al);  // 6 arrays of n (levels 10..15)

  int half = n / 2;
  int gridh = half / block;

  k_convert<<<2048, 256, 0, stream>>>(txy, txz, tyz, tab16, total);
  k_dense1011<<<gridh, block, 0, stream>>>(pts, tab16, slices, slices + (size_t)n,
                                           lc, total, half);
  for (int l = HASH_START; l < NLEV; ++l)
    k_hash_lvl<<<gridh, block, 0, stream>>>(pts, tab16, slices + (size_t)(l - 10) * n,
                                            lc.scale[l], lc.offset[l], total, half);
  k_final<<<n / 512, 512, 0, stream>>>(pts, tab16, slices, out, lc, total, n);
}

// Round 11
// 357.108 us; speedup vs baseline: 1.0493x; 1.0493x over previous
//
#include <hip/hip_runtime.h>
#include <hip/hip_fp16.h>
#include <cmath>

#define NLEV 16
#define HASH_START 12               // levels >= 12 use spatial hash ((r+1)^2 > 2^19)
#define HMASK ((1u << 19) - 1u)     // hash level size is exactly 2^19
#define HASH_PRIME 2654435761u
#define LDS_WORDS 14160             // offset[6]: entries of levels 0-5 (host-guarded)

typedef float    f4 __attribute__((ext_vector_type(4)));
typedef unsigned u4 __attribute__((ext_vector_type(4)));

struct LvlC {
  float scale[NLEV];
  unsigned stride[NLEV];   // res + 1
  unsigned offset[NLEV];   // cumulative param offset (multiple of 8)
};

__device__ __forceinline__ float2 h2f(unsigned u) {
  return __half22float2(__builtin_bit_cast(__half2, u));
}

// ---- pass 0: fp32 tables -> fp16 copies in ws ----
__global__ __launch_bounds__(256) void k_convert(
    const float2* __restrict__ t0, const float2* __restrict__ t1,
    const float2* __restrict__ t2, unsigned* __restrict__ dst, unsigned total)
{
  unsigned g = blockIdx.x * 256 + threadIdx.x;
  unsigned stp = gridDim.x * 256;
  unsigned tot3 = 3u * total;
  for (unsigned e = g; e < tot3; e += stp) {
    const float2* src; unsigned i = e;
    if (i < total)            { src = t0; }
    else if (i < 2u * total)  { src = t1; i -= total; }
    else                      { src = t2; i -= 2u * total; }
    float2 v = src[i];
    __half2 h = __floats2half2_rn(v.x, v.y);
    __builtin_nontemporal_store(__builtin_bit_cast(unsigned, h), dst + e);
  }
}

// ---- generic dense 2-level pair: 2 pts/thread, 24 uint2 gathers in flight ----
__global__ __launch_bounds__(256) void k_dense_pair(
    const float* __restrict__ pts, const unsigned* __restrict__ tab,
    unsigned* __restrict__ sA, unsigned* __restrict__ sB,
    float scA, unsigned stA, unsigned oA,
    float scB, unsigned stB, unsigned oB,
    unsigned total, int half)
{
  int t = blockIdx.x * 256 + threadIdx.x;
  if (t >= half) return;
  const int idx[2] = {t, t + half};

  float ua[2][3], ub[2][3];
#pragma unroll
  for (int k = 0; k < 2; ++k) {
    float u0 = (pts[3 * idx[k] + 0] + 1.f) * .5f;
    float u1 = (pts[3 * idx[k] + 1] + 1.f) * .5f;
    float u2 = (pts[3 * idx[k] + 2] + 1.f) * .5f;
    ua[k][0] = u0; ub[k][0] = u1;
    ua[k][1] = u0; ub[k][1] = u2;
    ua[k][2] = u1; ub[k][2] = u2;
  }
  const float sc[2] = {scA, scB};
  const unsigned st[2] = {stA, stB}, o[2] = {oA, oB};

  uint2 g[2][2][3][2];
  float rx[2][2][3], ry[2][2][3];
#pragma unroll
  for (int k = 0; k < 2; ++k)
#pragma unroll
    for (int l = 0; l < 2; ++l)
#pragma unroll
      for (int p = 0; p < 3; ++p) {
        float px = ua[k][p] * sc[l] + .5f, py = ub[k][p] * sc[l] + .5f;
        float fx = floorf(px), fy = floorf(py);
        rx[k][l][p] = px - fx; ry[k][l][p] = py - fy;
        unsigned i00 = (unsigned)fx + (unsigned)fy * st[l] + o[l];
        const unsigned* tp = tab + (size_t)p * total;
        g[k][l][p][0] = *reinterpret_cast<const uint2*>(tp + i00);
        g[k][l][p][1] = *reinterpret_cast<const uint2*>(tp + i00 + st[l]);
      }

#pragma unroll
  for (int k = 0; k < 2; ++k)
#pragma unroll
    for (int l = 0; l < 2; ++l) {
      float s0 = 0.f, s1 = 0.f;
#pragma unroll
      for (int p = 0; p < 3; ++p) {
        float x = rx[k][l][p], y = ry[k][l][p];
        float w00 = (1.f - x) * (1.f - y), w10 = x * (1.f - y);
        float w01 = (1.f - x) * y,          w11 = x * y;
        float2 f00 = h2f(g[k][l][p][0].x), f10 = h2f(g[k][l][p][0].y);
        float2 f01 = h2f(g[k][l][p][1].x), f11 = h2f(g[k][l][p][1].y);
        s0 += w00 * f00.x + w10 * f10.x + w01 * f01.x + w11 * f11.x;
        s1 += w00 * f00.y + w10 * f10.y + w01 * f01.y + w11 * f11.y;
      }
      unsigned hv = __builtin_bit_cast(unsigned, __floats2half2_rn(s0, s1));
      __builtin_nontemporal_store(hv, (l ? sB : sA) + idx[k]);
    }
}

// even-x0 trick: (x0+1)^hy == (x0^hy)^1 when x0 even -> aligned uint2 pair
__device__ __forceinline__ void hash_row(
    const unsigned* __restrict__ tp, unsigned x0, unsigned hy,
    unsigned& g0, unsigned& g1)
{
  unsigned a0 = (x0 ^ hy) & HMASK;
  if ((x0 & 1u) == 0u) {
    uint2 v = *reinterpret_cast<const uint2*>(tp + (a0 & ~1u));
    bool hi = (a0 & 1u) != 0u;
    g0 = hi ? v.y : v.x;
    g1 = hi ? v.x : v.y;
  } else {
    g0 = tp[a0];
    g1 = tp[((x0 + 1u) ^ hy) & HMASK];
  }
}

// ---- one hash level, all 3 planes, 2 pts/thread ----
__global__ __launch_bounds__(256) void k_hash_lvl(
    const float* __restrict__ pts, const unsigned* __restrict__ tab,
    unsigned* __restrict__ slice, float sc, unsigned o, unsigned total, int half)
{
  int t = blockIdx.x * 256 + threadIdx.x;
  if (t >= half) return;
  const int idx[2] = {t, t + half};

  float ua[2][3], ub[2][3];
#pragma unroll
  for (int k = 0; k < 2; ++k) {
    float u0 = (pts[3 * idx[k] + 0] + 1.f) * .5f;
    float u1 = (pts[3 * idx[k] + 1] + 1.f) * .5f;
    float u2 = (pts[3 * idx[k] + 2] + 1.f) * .5f;
    ua[k][0] = u0; ub[k][0] = u1;
    ua[k][1] = u0; ub[k][1] = u2;
    ua[k][2] = u1; ub[k][2] = u2;
  }

  unsigned g[2][3][4];
  float rx[2][3], ry[2][3];
#pragma unroll
  for (int k = 0; k < 2; ++k)
#pragma unroll
    for (int p = 0; p < 3; ++p) {
      float px = ua[k][p] * sc + .5f, py = ub[k][p] * sc + .5f;
      float fx = floorf(px), fy = floorf(py);
      rx[k][p] = px - fx; ry[k][p] = py - fy;
      unsigned x0 = (unsigned)fx, y0 = (unsigned)fy;
      unsigned hy0 = y0 * HASH_PRIME, hy1 = hy0 + HASH_PRIME;
      const unsigned* tp = tab + (size_t)p * total + o;
      hash_row(tp, x0, hy0, g[k][p][0], g[k][p][1]);
      hash_row(tp, x0, hy1, g[k][p][2], g[k][p][3]);
    }

#pragma unroll
  for (int k = 0; k < 2; ++k) {
    float s0 = 0.f, s1 = 0.f;
#pragma unroll
    for (int p = 0; p < 3; ++p) {
      float x = rx[k][p], y = ry[k][p];
      float w00 = (1.f - x) * (1.f - y), w10 = x * (1.f - y);
      float w01 = (1.f - x) * y,          w11 = x * y;
      float2 f00 = h2f(g[k][p][0]), f10 = h2f(g[k][p][1]);
      float2 f01 = h2f(g[k][p][2]), f11 = h2f(g[k][p][3]);
      s0 += w00 * f00.x + w10 * f10.x + w01 * f01.x + w11 * f11.x;
      s1 += w00 * f00.y + w10 * f10.y + w01 * f01.y + w11 * f11.y;
    }
    __builtin_nontemporal_store(
        __builtin_bit_cast(unsigned, __floats2half2_rn(s0, s1)), slice + idx[k]);
  }
}

// ---- final: LDS levels 0-5 (R9 single-phase staging) + merge NSLICE slices.
//      DO69: compute levels 6-9 in-kernel (6-slice fallback path). ----
template <bool DO69>
__global__ __launch_bounds__(512) void k_final(
    const float* __restrict__ pts, const unsigned* __restrict__ tab,
    const unsigned* __restrict__ slices,   // DO69 ? 6 x n (lvl10..15) : 10 x n (lvl6..15)
    float* __restrict__ out, LvlC lc, unsigned total, int n)
{
  __shared__ unsigned lds[LDS_WORDS];
  int i = blockIdx.x * 512 + threadIdx.x;  // n % 512 == 0 (host-guarded)

  const int NS = DO69 ? 6 : 10;
  unsigned sl[DO69 ? 6 : 10];
#pragma unroll
  for (int j = 0; j < NS; ++j) sl[j] = slices[(size_t)j * n + i];

  float u0 = (pts[3 * i + 0] + 1.f) * .5f;
  float u1 = (pts[3 * i + 1] + 1.f) * .5f;
  float u2 = (pts[3 * i + 2] + 1.f) * .5f;
  const float ua[3] = {u0, u0, u1}, ub[3] = {u1, u2, u2};

  float res[12];
#pragma unroll
  for (int j = 0; j < 12; ++j) res[j] = 0.f;

  for (int p = 0; p < 3; ++p) {
    if (p) __syncthreads();
    const u4* src = reinterpret_cast<const u4*>(tab + (size_t)p * total);
    for (unsigned e = threadIdx.x; e < LDS_WORDS / 4; e += 512)
      reinterpret_cast<u4*>(lds)[e] = src[e];
    __syncthreads();
#pragma unroll
    for (int l = 0; l < 6; ++l) {
      float px = ua[p] * lc.scale[l] + .5f, py = ub[p] * lc.scale[l] + .5f;
      float fx = floorf(px), fy = floorf(py);
      float x = px - fx, y = py - fy;
      unsigned st = lc.stride[l];
      unsigned i00 = (unsigned)fx + (unsigned)fy * st + lc.offset[l];
      float2 f00 = h2f(lds[i00]),      f10 = h2f(lds[i00 + 1]);
      float2 f01 = h2f(lds[i00 + st]), f11 = h2f(lds[i00 + st + 1]);
      float w00 = (1.f - x) * (1.f - y), w10 = x * (1.f - y);
      float w01 = (1.f - x) * y,          w11 = x * y;
      res[2 * l + 0] += w00 * f00.x + w10 * f10.x + w01 * f01.x + w11 * f11.x;
      res[2 * l + 1] += w00 * f00.y + w10 * f10.y + w01 * f01.y + w11 * f11.y;
    }
  }

  float v[32];
#pragma unroll
  for (int j = 0; j < 12; ++j) v[j] = res[j];

  if (DO69) {
    // levels 6-9 computed here (fallback when ws can't hold 10 slices)
#pragma unroll
    for (int grp = 0; grp < 2; ++grp) {
      uint2 g[2][3][2];
      float gx[2][3], gy[2][3];
#pragma unroll
      for (int h = 0; h < 2; ++h) {
        const int l = 6 + 2 * grp + h;
        const float sc = lc.scale[l];
        const unsigned st = lc.stride[l], o = lc.offset[l];
#pragma unroll
        for (int p = 0; p < 3; ++p) {
          float px = ua[p] * sc + .5f, py = ub[p] * sc + .5f;
          float fx = floorf(px), fy = floorf(py);
          gx[h][p] = px - fx; gy[h][p] = py - fy;
          unsigned i00 = (unsigned)fx + (unsigned)fy * st + o;
          const unsigned* tp = tab + (size_t)p * total;
          g[h][p][0] = *reinterpret_cast<const uint2*>(tp + i00);
          g[h][p][1] = *reinterpret_cast<const uint2*>(tp + i00 + st);
        }
      }
#pragma unroll
      for (int h = 0; h < 2; ++h) {
        float s0 = 0.f, s1 = 0.f;
#pragma unroll
        for (int p = 0; p < 3; ++p) {
          float x = gx[h][p], y = gy[h][p];
          float w00 = (1.f - x) * (1.f - y), w10 = x * (1.f - y);
          float w01 = (1.f - x) * y,          w11 = x * y;
          float2 f00 = h2f(g[h][p][0].x), f10 = h2f(g[h][p][0].y);
          float2 f01 = h2f(g[h][p][1].x), f11 = h2f(g[h][p][1].y);
          s0 += w00 * f00.x + w10 * f10.x + w01 * f01.x + w11 * f11.x;
          s1 += w00 * f00.y + w10 * f10.y + w01 * f01.y + w11 * f11.y;
        }
        v[12 + 4 * grp + 2 * h + 0] = s0;
        v[12 + 4 * grp + 2 * h + 1] = s1;
      }
    }
#pragma unroll
    for (int j = 0; j < 6; ++j) {
      float2 f = h2f(sl[j]);
      v[20 + 2 * j] = f.x; v[20 + 2 * j + 1] = f.y;
    }
  } else {
#pragma unroll
    for (int j = 0; j < 10; ++j) {
      float2 f = h2f(sl[j]);
      v[12 + 2 * j] = f.x; v[12 + 2 * j + 1] = f.y;
    }
  }

  float4* o4 = (float4*)(out + (size_t)i * 32);
#pragma unroll
  for (int j = 0; j < 8; ++j)
    o4[j] = make_float4(v[4 * j], v[4 * j + 1], v[4 * j + 2], v[4 * j + 3]);
}

// ---- fallback: monolithic fp32 (guards failed) ----
__global__ __launch_bounds__(256) void k_fallback(
    const float* __restrict__ pts, const float2* __restrict__ txy,
    const float2* __restrict__ txz, const float2* __restrict__ tyz,
    float* __restrict__ out, LvlC lc, int n)
{
  int i = blockIdx.x * 256 + threadIdx.x;
  if (i >= n) return;
  float u0 = (pts[3 * i + 0] + 1.f) * .5f;
  float u1 = (pts[3 * i + 1] + 1.f) * .5f;
  float u2 = (pts[3 * i + 2] + 1.f) * .5f;
  const float ua[3] = {u0, u0, u1}, ub[3] = {u1, u2, u2};
  const float2* tabs[3] = {txy, txz, tyz};
  float acc[32];
#pragma unroll
  for (int j = 0; j < 32; ++j) acc[j] = 0.f;
#pragma unroll
  for (int l = 0; l < NLEV; ++l) {
    const float sc = lc.scale[l];
    const unsigned o = lc.offset[l], s = lc.stride[l];
#pragma unroll
    for (int p = 0; p < 3; ++p) {
      const float2* t = tabs[p];
      float px = ua[p] * sc + .5f, py = ub[p] * sc + .5f;
      float fx = floorf(px), fy = floorf(py);
      float rx = px - fx, ry = py - fy;
      unsigned x0 = (unsigned)fx, y0 = (unsigned)fy;
      float w00 = (1.f - rx) * (1.f - ry), w10 = rx * (1.f - ry);
      float w01 = (1.f - rx) * ry,          w11 = rx * ry;
      float2 f00, f10, f01, f11;
      if (l >= HASH_START) {
        unsigned hy0 = y0 * HASH_PRIME, hy1 = hy0 + HASH_PRIME;
        f00 = t[o + ((x0 ^ hy0) & HMASK)];
        f10 = t[o + (((x0 + 1u) ^ hy0) & HMASK)];
        f01 = t[o + ((x0 ^ hy1) & HMASK)];
        f11 = t[o + (((x0 + 1u) ^ hy1) & HMASK)];
      } else {
        unsigned i00 = x0 + y0 * s;
        float4 r0 = *reinterpret_cast<const float4*>(t + o + i00);
        float4 r1 = *reinterpret_cast<const float4*>(t + o + i00 + s);
        f00 = make_float2(r0.x, r0.y); f10 = make_float2(r0.z, r0.w);
        f01 = make_float2(r1.x, r1.y); f11 = make_float2(r1.z, r1.w);
      }
      acc[2 * l + 0] += w00 * f00.x + w10 * f10.x + w01 * f01.x + w11 * f11.x;
      acc[2 * l + 1] += w00 * f00.y + w10 * f10.y + w01 * f01.y + w11 * f11.y;
    }
  }
  float4* o4 = (float4*)(out + (size_t)i * 32);
#pragma unroll
  for (int j = 0; j < 8; ++j)
    o4[j] = make_float4(acc[4 * j], acc[4 * j + 1], acc[4 * j + 2], acc[4 * j + 3]);
}

static unsigned compute_levels(LvlC* lc)
{
  // Mirrors Python _level_constants() with identical double-precision ops.
  const double pls = std::pow(2.0, std::log2(2048.0 / 16.0) / 15.0);
  unsigned long long off = 0;
  for (int l = 0; l < NLEV; ++l) {
    double s = 16.0 * std::pow(pls, (double)l) - 1.0;
    lc->scale[l] = (float)s;
    long long r = (long long)std::ceil(s) + 1;
    long long dense = (r + 1) * (r + 1);
    long long sz = dense < (1LL << 19) ? dense : (1LL << 19);
    sz = ((sz + 7) / 8) * 8;
    lc->stride[l] = (unsigned)(r + 1);
    lc->offset[l] = (unsigned)off;
    off += (unsigned long long)sz;
  }
  return (unsigned)off;
}

extern "C" void kernel_launch(void* const* d_in, const int* in_sizes, int n_in,
                              void* d_out, int out_size, void* d_ws, size_t ws_size,
                              hipStream_t stream) {
  const float*  pts = (const float*)d_in[0];
  const float2* txy = (const float2*)d_in[1];
  const float2* txz = (const float2*)d_in[2];
  const float2* tyz = (const float2*)d_in[3];
  float* out = (float*)d_out;
  int n = in_sizes[0] / 3;  // 1048576 points

  LvlC lc;
  unsigned total = compute_levels(&lc);

  size_t tab_bytes = (size_t)3 * total * 4;
  size_t tab_al = (tab_bytes + 255) & ~(size_t)255;
  size_t need10 = tab_al + (size_t)10 * n * 4;
  size_t need6  = tab_al + (size_t)6 * n * 4;

  bool base_ok = (n % 512 == 0) && (lc.offset[6] == LDS_WORDS);
  for (int l = HASH_START; l < NLEV; ++l) {
    unsigned sz = ((l + 1 < NLEV) ? lc.offset[l + 1] : total) - lc.offset[l];
    base_ok = base_ok && (sz == (1u << 19));
  }

  int block = 256;
  int grid = (n + block - 1) / block;
  if (!base_ok || ws_size < need6) {
    k_fallback<<<grid, block, 0, stream>>>(pts, txy, txz, tyz, out, lc, n);
    return;
  }

  unsigned* tab16 = (unsigned*)d_ws;
  unsigned* slices = (unsigned*)((char*)d_ws + tab_al);
  int half = n / 2;
  int gridh = half / block;

  k_convert<<<2048, 256, 0, stream>>>(txy, txz, tyz, tab16, total);

  if (ws_size >= need10) {
    // 10-slice path: all divergent-gather levels run at the TA issue cap
    for (int grp = 0; grp < 3; ++grp) {
      int lA = 6 + 2 * grp, lB = lA + 1;
      k_dense_pair<<<gridh, block, 0, stream>>>(
          pts, tab16,
          slices + (size_t)(lA - 6) * n, slices + (size_t)(lB - 6) * n,
          lc.scale[lA], lc.stride[lA], lc.offset[lA],
          lc.scale[lB], lc.stride[lB], lc.offset[lB], total, half);
    }
    for (int l = HASH_START; l < NLEV; ++l)
      k_hash_lvl<<<gridh, block, 0, stream>>>(pts, tab16, slices + (size_t)(l - 6) * n,
                                              lc.scale[l], lc.offset[l], total, half);
    k_final<false><<<n / 512, 512, 0, stream>>>(pts, tab16, slices, out, lc, total, n);
  } else {
    // 6-slice path (R9 structure)
    k_dense_pair<<<gridh, block, 0, stream>>>(
        pts, tab16, slices, slices + (size_t)n,
        lc.scale[10], lc.stride[10], lc.offset[10],
        lc.scale[11], lc.stride[11], lc.offset[11], total, half);
    for (int l = HASH_START; l < NLEV; ++l)
      k_hash_lvl<<<gridh, block, 0, stream>>>(pts, tab16, slices + (size_t)(l - 10) * n,
                                              lc.scale[l], lc.offset[l], total, half);
    k_final<true><<<n / 512, 512, 0, stream>>>(pts, tab16, slices, out, lc, total, n);
  }
}